// Round 13
// baseline (118.028 us; speedup 1.0000x reference)
//
#include <hip/hip_runtime.h>
#include <math.h>

#define BB  64
#define WW  128
#define NN  64
#define HIDN 77

__device__ __forceinline__ float b2f(unsigned short u) {
  union { float f; unsigned int i; } v; v.i = ((unsigned int)u) << 16; return v.f;
}
__device__ __forceinline__ unsigned short f2b(float f) {
  unsigned int x = __float_as_uint(f);
  unsigned int r = (x + 0x7FFFu + ((x >> 16) & 1u)) >> 16;   // RNE
  return (unsigned short)r;
}

// ================= K1: fused front (bf16-staged weights, 72.4 KB LDS, 2 blk/CU) =================
// hA=(S@[x|emb])@Wg -> MLP -> xs, out_rec. Block 1 tail-builds GAT CSR.
__global__ __launch_bounds__(512, 4) void k_front(
    const float* __restrict__ x, const float* __restrict__ emb,
    const float* __restrict__ wg, const float* __restrict__ gcn_b,
    const float* __restrict__ w1, const float* __restrict__ b1,
    const float* __restrict__ w2, const float* __restrict__ b2,
    const int* __restrict__ gl_ei, int E_gl,
    const int* __restrict__ gat_ei, int E_gat,
    float* __restrict__ xs, float* __restrict__ out_rec,
    int* __restrict__ gat_off, int* __restrict__ gat_list) {
  __shared__ float smem[18112];   // 72,448 B
  unsigned short* WB = (unsigned short*)smem;   // Ws bf16 [140][128]=35840B; later W1 [128][80]; later W2 [77][128]
  float* XA   = smem + 8960;     // 16x144 (S@[x|emb] -> hA in place)
  float* Sm   = smem + 11264;    // 16x68
  float* xbt  = smem + 12352;    // 16x132
  float* hm   = smem + 14464;    // 16x80
  float* recT = smem + 15744;    // 128x17
  float* gbb  = smem + 17920;    // 128
  int*   cnt  = (int*)(smem + 18048);  // 64
  float* scr4 = smem + 14464;    // P4 combine scratch (2048 f over hm+recT front)
  float* scr6 = smem + 15744;    // P6 combine scratch (1280 f over recT)

  int tid = threadIdx.x;
  int r0 = blockIdx.x * 16;
  int b = r0 >> 6, n0 = r0 & 63;
  const float* xb  = x + (size_t)b * 8192;
  const float* xb2 = xb + n0;

  // P0: stage Ws (bf16), xbt; init Sm, cnt, gbb
  {
    const float4* W4 = (const float4*)wg;
    ushort4* WB4 = (ushort4*)WB;
    for (int t = tid; t < 4480; t += 512) {
      float4 w = W4[t];
      ushort4 o; o.x = f2b(w.x); o.y = f2b(w.y); o.z = f2b(w.z); o.w = f2b(w.w);
      WB4[t] = o;
    }
  }
  for (int t = tid; t < 2048; t += 512) {
    int w = t >> 4, i = t & 15;
    xbt[i * 132 + w] = xb2[w * 64 + i];
  }
  for (int t = tid; t < 1088; t += 512) Sm[t] = 0.f;
  if (tid < 128) gbb[tid] = gcn_b[tid];
  if (tid < 64) cnt[tid] = 1;  // self-loop
  __syncthreads();

  // P1: edge scan: degree + indicator
  for (int e = tid; e < E_gl; e += 512) {
    int dst = gl_ei[BB * E_gl + e];
    atomicAdd(&cnt[dst], 1);
    int d = dst - n0;
    if ((unsigned)d < 16u) Sm[d * 68 + gl_ei[e]] = 1.0f;
  }
  __syncthreads();

  // P2: scale indicators -> coefs + self-loop
  for (int t = tid; t < 1088; t += 512) {
    int i = t / 68, s = t % 68;
    if (s < 64) {
      float di = rsqrtf((float)cnt[n0 + i]);
      float v = Sm[t] * rsqrtf((float)cnt[s]) * di;
      if (s == n0 + i) v += di * di;
      Sm[t] = v;
    }
  }
  __syncthreads();

  // P3: XA[i][w] = sum_s Sm[i][s]*x[b][w][s]; emb cols
  {
    int i = tid >> 5, tw = tid & 31;
    const float* Sr = Sm + i * 68;
    float o0 = 0, o1 = 0, o2 = 0, o3 = 0;
#pragma unroll 4
    for (int s4 = 0; s4 < 16; s4++) {
      float4 sv = *(const float4*)&Sr[s4 * 4];
      float4 x0 = *(const float4*)&xb[(tw)*64 + s4 * 4];
      float4 x1 = *(const float4*)&xb[(tw + 32) * 64 + s4 * 4];
      float4 x2 = *(const float4*)&xb[(tw + 64) * 64 + s4 * 4];
      float4 x3 = *(const float4*)&xb[(tw + 96) * 64 + s4 * 4];
      o0 += sv.x * x0.x + sv.y * x0.y + sv.z * x0.z + sv.w * x0.w;
      o1 += sv.x * x1.x + sv.y * x1.y + sv.z * x1.z + sv.w * x1.w;
      o2 += sv.x * x2.x + sv.y * x2.y + sv.z * x2.z + sv.w * x2.w;
      o3 += sv.x * x3.x + sv.y * x3.y + sv.z * x3.z + sv.w * x3.w;
    }
    float* Xr = XA + i * 144;
    Xr[tw] = o0; Xr[tw + 32] = o1; Xr[tw + 64] = o2; Xr[tw + 96] = o3;
  }
  if (tid < 192) {
    int i = tid / 12, j = tid % 12;
    const float* Sr = Sm + i * 68;
    float a = 0.f;
    for (int s = 0; s < 64; s++) a += Sr[s] * emb[s * 12 + j];
    XA[i * 144 + 128 + j] = a;
  }
  __syncthreads();

  // P4: GEMM1 (16x140 @ 140x128 bf16-W), 2r x 4c x k-split-2
  {
    int half = tid >> 8, t = tid & 255;
    int ty2 = t >> 5, txc = t & 31;
    int c0 = txc * 4;
    float a00 = 0, a01 = 0, a02 = 0, a03 = 0, a10 = 0, a11 = 0, a12 = 0, a13 = 0;
    const float* A0 = XA + (ty2 * 2) * 144;
    const float* A1 = A0 + 144;
    int k0 = half * 70;
#pragma unroll 5
    for (int k = k0; k < k0 + 70; k++) {
      ushort4 wv = *(const ushort4*)&WB[k * 128 + c0];
      float wx = b2f(wv.x), wy = b2f(wv.y), wz = b2f(wv.z), ww = b2f(wv.w);
      float a0 = A0[k], a1 = A1[k];
      a00 += a0 * wx; a01 += a0 * wy; a02 += a0 * wz; a03 += a0 * ww;
      a10 += a1 * wx; a11 += a1 * wy; a12 += a1 * wz; a13 += a1 * ww;
    }
    if (half) {
      *(float4*)&scr4[t * 8]     = make_float4(a00, a01, a02, a03);
      *(float4*)&scr4[t * 8 + 4] = make_float4(a10, a11, a12, a13);
    }
    __syncthreads();   // all WB(Ws)/XA reads + scr4 writes done
    // combine (!half) into XA; concurrently stage W1 bf16 over WB (all threads)
    if (!half) {
      float4 p0 = *(const float4*)&scr4[t * 8];
      float4 p1 = *(const float4*)&scr4[t * 8 + 4];
      float4 bv = *(const float4*)&gbb[c0];
      *(float4*)&XA[(ty2 * 2) * 144 + c0] = make_float4(
          fmaxf(a00 + p0.x + bv.x, 0.f), fmaxf(a01 + p0.y + bv.y, 0.f),
          fmaxf(a02 + p0.z + bv.z, 0.f), fmaxf(a03 + p0.w + bv.w, 0.f));
      *(float4*)&XA[(ty2 * 2 + 1) * 144 + c0] = make_float4(
          fmaxf(a10 + p1.x + bv.x, 0.f), fmaxf(a11 + p1.y + bv.y, 0.f),
          fmaxf(a12 + p1.z + bv.z, 0.f), fmaxf(a13 + p1.w + bv.w, 0.f));
    }
    for (int q = tid; q < 10240; q += 512) {
      int k = q / 80, c = q % 80;
      WB[q] = (c < HIDN) ? f2b(w1[k * HIDN + c]) : (unsigned short)0;
    }
  }
  __syncthreads();

  // P6: hm = tanh(hA @ W1 + b1) (bf16-W), 2r x 4c x k-split-2, 320 threads
  {
    bool act = tid < 320;
    int half6 = (tid >= 160) ? 1 : 0;
    int s = half6 ? tid - 160 : tid;
    int rp = s / 20, cg = s % 20;
    int c0 = cg * 4;
    float a00 = 0, a01 = 0, a02 = 0, a03 = 0, a10 = 0, a11 = 0, a12 = 0, a13 = 0;
    if (act) {
      const float* A0 = XA + (rp * 2) * 144;
      const float* A1 = A0 + 144;
      int k0 = half6 * 64;
#pragma unroll 4
      for (int k = k0; k < k0 + 64; k++) {
        ushort4 wv = *(const ushort4*)&WB[k * 80 + c0];
        float wx = b2f(wv.x), wy = b2f(wv.y), wz = b2f(wv.z), ww = b2f(wv.w);
        float a0 = A0[k], a1 = A1[k];
        a00 += a0 * wx; a01 += a0 * wy; a02 += a0 * wz; a03 += a0 * ww;
        a10 += a1 * wx; a11 += a1 * wy; a12 += a1 * wz; a13 += a1 * ww;
      }
      if (half6) {
        *(float4*)&scr6[s * 8]     = make_float4(a00, a01, a02, a03);
        *(float4*)&scr6[s * 8 + 4] = make_float4(a10, a11, a12, a13);
      }
    }
    __syncthreads();
    if (act && !half6) {
      float4 p0 = *(const float4*)&scr6[s * 8];
      float4 p1 = *(const float4*)&scr6[s * 8 + 4];
      float r0v[4] = {a00 + p0.x, a01 + p0.y, a02 + p0.z, a03 + p0.w};
      float r1v[4] = {a10 + p1.x, a11 + p1.y, a12 + p1.z, a13 + p1.w};
#pragma unroll
      for (int j = 0; j < 4; j++) {
        int c = c0 + j;
        float bb = (c < HIDN) ? b1[c] : 0.f;
        hm[(rp * 2) * 80 + c]     = tanhf(r0v[j] + bb);
        hm[(rp * 2 + 1) * 80 + c] = tanhf(r1v[j] + bb);
      }
    }
  }
  __syncthreads();
  // P7: stage W2 bf16 over WB
  {
    const float4* w24 = (const float4*)w2;
    ushort4* WB4 = (ushort4*)WB;
    for (int t = tid; t < 2464; t += 512) {
      float4 w = w24[t];
      ushort4 o; o.x = f2b(w.x); o.y = f2b(w.y); o.z = f2b(w.z); o.w = f2b(w.w);
      WB4[t] = o;
    }
  }
  __syncthreads();

  // P8: x_rec = tanh(hm @ W2 + b2); xs; recT  (2r x 4c, 256 threads)
  {
    if (tid < 256) {
      int ty2 = tid >> 5, txc = tid & 31;
      int c0 = txc * 4;
      float a00 = 0, a01 = 0, a02 = 0, a03 = 0, a10 = 0, a11 = 0, a12 = 0, a13 = 0;
      const float* H0 = hm + (ty2 * 2) * 80;
      const float* H1 = H0 + 80;
#pragma unroll 4
      for (int k = 0; k < HIDN; k++) {
        ushort4 wv = *(const ushort4*)&WB[k * 128 + c0];
        float wx = b2f(wv.x), wy = b2f(wv.y), wz = b2f(wv.z), ww = b2f(wv.w);
        float a0 = H0[k], a1 = H1[k];
        a00 += a0 * wx; a01 += a0 * wy; a02 += a0 * wz; a03 += a0 * ww;
        a10 += a1 * wx; a11 += a1 * wy; a12 += a1 * wz; a13 += a1 * ww;
      }
      float4 bv = *(const float4*)&b2[c0];
      float x00 = tanhf(a00 + bv.x), x01 = tanhf(a01 + bv.y), x02 = tanhf(a02 + bv.z), x03 = tanhf(a03 + bv.w);
      float x10 = tanhf(a10 + bv.x), x11 = tanhf(a11 + bv.y), x12 = tanhf(a12 + bv.z), x13 = tanhf(a13 + bv.w);
      int row0 = ty2 * 2;
      const float* X0 = xbt + row0 * 132;
      const float* X1 = X0 + 132;
      *(float4*)&xs[(size_t)(r0 + row0) * 128 + c0] =
          make_float4(X0[c0] + x00, X0[c0 + 1] + x01, X0[c0 + 2] + x02, X0[c0 + 3] + x03);
      *(float4*)&xs[(size_t)(r0 + row0 + 1) * 128 + c0] =
          make_float4(X1[c0] + x10, X1[c0 + 1] + x11, X1[c0 + 2] + x12, X1[c0 + 3] + x13);
      recT[(c0 + 0) * 17 + row0] = x00; recT[(c0 + 1) * 17 + row0] = x01;
      recT[(c0 + 2) * 17 + row0] = x02; recT[(c0 + 3) * 17 + row0] = x03;
      recT[(c0 + 0) * 17 + row0 + 1] = x10; recT[(c0 + 1) * 17 + row0 + 1] = x11;
      recT[(c0 + 2) * 17 + row0 + 1] = x12; recT[(c0 + 3) * 17 + row0 + 1] = x13;
    }
  }
  __syncthreads();
  // P9: out_rec
  float* orc = out_rec + (size_t)b * 8192 + n0;
  for (int t = tid; t < 2048; t += 512) {
    int w = t >> 4, i = t & 15;
    orc[w * 64 + i] = recT[w * 17 + i];
  }

  // ---- tail (block 1): build GAT CSR ----
  if (blockIdx.x == 1) {
    __syncthreads();
    int* ip   = (int*)smem;
    int* offs = ip;
    int* cur  = ip + 65;
    int* cntg = ip + 129;
    int* lst  = ip + 193;
    if (tid < 64) cntg[tid] = 1;
    __syncthreads();
    for (int e = tid; e < E_gat; e += 512) atomicAdd(&cntg[gat_ei[BB * E_gat + e]], 1);
    __syncthreads();
    if (tid == 0) { int s = 0; for (int n = 0; n < 64; n++) { offs[n] = s; s += cntg[n]; } offs[64] = s; }
    __syncthreads();
    if (tid < 64) cur[tid] = offs[tid];
    __syncthreads();
    for (int e = tid; e < E_gat; e += 512) {
      int src = gat_ei[e], dst = gat_ei[BB * E_gat + e];
      lst[atomicAdd(&cur[dst], 1)] = src;
    }
    if (tid < 64) lst[atomicAdd(&cur[tid], 1)] = tid;
    __syncthreads();
    if (tid < 65) gat_off[tid] = offs[tid];
    int tot = offs[64];
    for (int t = tid; t < tot; t += 512) gat_list[t] = lst[t];
  }
}

// ================= K2: left/right projections + (blocks>=2048) GAT matvecs =================
__global__ __launch_bounds__(256) void k_lr(const float* __restrict__ xs, const float* __restrict__ ta_w,
                                            const float* __restrict__ ta_b, float* __restrict__ leftT,
                                            float* __restrict__ rightT,
                                            const float* __restrict__ gat_w, const float* __restrict__ asrc,
                                            const float* __restrict__ adst, const float* __restrict__ fcw,
                                            const float* __restrict__ gat_b, float* __restrict__ VAV) {
  if (blockIdx.x >= 2048) {
    int which = blockIdx.x - 2048;
    int tid = threadIdx.x;
    const float* vecg = (which == 0) ? asrc : (which == 1) ? adst : fcw;
    if (tid < 128) {
      float acc = 0.f;
#pragma unroll 4
      for (int k = 0; k < 128; k++) acc += gat_w[tid * 128 + k] * vecg[k];
      VAV[which * 128 + tid] = acc;
    }
    if (which == 2) {
      __shared__ float red[128];
      if (tid < 128) red[tid] = gat_b[tid] * fcw[tid];
      __syncthreads();
      if (tid == 0) {
        float s = 0.f;
        for (int i = 0; i < 128; i++) s += red[i];
        VAV[384] = s;
      }
    }
    return;
  }
  int wave = threadIdx.x >> 6, lane = threadIdx.x & 63;
  int idx = blockIdx.x * 4 + wave;
  int b = idx >> 7, e = idx & 127;
  int c = lane * 2;
  const float* xsb = xs + (size_t)b * 8192;
  float lx = 0, ly = 0, rx = 0, ry = 0;
#pragma unroll 4
  for (int n = 0; n < 64; n++) {
    float wl = ta_w[n * 128 + e];
    float wr = ta_w[(64 + n) * 128 + e];
    float2 xv = *(const float2*)&xsb[n * 128 + c];
    lx += wl * xv.x; ly += wl * xv.y;
    rx += wr * xv.x; ry += wr * xv.y;
  }
  float tb = ta_b[e];
  *(float2*)&leftT[((size_t)b * 128 + e) * 128 + c] = make_float2(lx + tb, ly + tb);
  *(float2*)&rightT[((size_t)b * 128 + e) * 128 + c] = make_float2(rx, ry);
}

// ================= K3: fused e-score (4x4 tile) + softmax + PV + tanh =================
__global__ __launch_bounds__(512) void k_attn(const float* __restrict__ LEFT_, const float* __restrict__ RIGHT_,
                                              const float* __restrict__ ta_a, const float* __restrict__ ta_bias,
                                              const float* __restrict__ xs, float* __restrict__ ht) {
  __shared__ float Rf[128 * 128];
  __shared__ float Lh[32 * 132];
  __shared__ float xsT[128 * 68];
  __shared__ float av2[128], av6[128], uu[32], vv[128];
  int tid = threadIdx.x;
  int b = blockIdx.x >> 2, q = blockIdx.x & 3;
  int i0 = q * 32;

  {
    const float4* R4 = (const float4*)(RIGHT_ + (size_t)b * 16384);
    float4* Rf4 = (float4*)Rf;
#pragma unroll
    for (int t = 0; t < 8; t++) Rf4[tid + t * 512] = R4[tid + t * 512];
  }
  {
    const float* Lp = LEFT_ + (size_t)b * 16384 + i0;
#pragma unroll
    for (int t = 0; t < 8; t++) {
      int idx = tid + t * 512;
      Lh[idx] = Lp[(idx >> 5) * 128 + (idx & 31)];
    }
  }
  {
    const float* xsb = xs + (size_t)b * 8192;
#pragma unroll
    for (int t = 0; t < 16; t++) {
      int idx = tid + t * 512;
      xsT[(idx & 127) * 68 + (idx >> 7)] = xsb[idx];
    }
  }
  if (tid < 128) { float a = ta_a[tid]; av2[tid] = 0.4f * a; av6[tid] = 0.6f * a; }
  __syncthreads();

  if (tid < 160) {
    float acc = 0.f;
    if (tid < 128) {
      for (int e = 0; e < 128; e++) acc += av6[e] * Rf[e * 128 + tid];
      vv[tid] = acc;
    } else {
      int i = tid - 128;
      for (int e = 0; e < 128; e++) acc += av6[e] * Lh[e * 32 + i];
      uu[i] = acc;
    }
  }
  __syncthreads();

  bool act = tid < 256;
  int tj = tid & 31, ti = (tid >> 5) & 7;
  float p[4][4];
  if (act) {
    float acc[4][4];
#pragma unroll
    for (int a = 0; a < 4; a++)
#pragma unroll
      for (int j = 0; j < 4; j++) acc[a][j] = 0.f;
#pragma unroll 2
    for (int e = 0; e < 128; e++) {
      float4 Lv = *(const float4*)&Lh[e * 32 + ti * 4];
      float4 Rv = *(const float4*)&Rf[e * 128 + tj * 4];
      float ae = av2[e];
      float La[4] = {Lv.x, Lv.y, Lv.z, Lv.w};
      float Ra[4] = {Rv.x, Rv.y, Rv.z, Rv.w};
#pragma unroll
      for (int a = 0; a < 4; a++)
#pragma unroll
        for (int j = 0; j < 4; j++) {
          float t = La[a] + Ra[j];
          acc[a][j] += ae * fabsf(t);
        }
    }
#pragma unroll
    for (int a = 0; a < 4; a++) {
      int i = i0 + ti * 4 + a;
      float uvi = uu[ti * 4 + a];
      float4 bv = *(const float4*)&ta_bias[(size_t)i * 128 + tj * 4];
      float v0 = acc[a][0] + bv.x + uvi + vv[tj * 4 + 0];
      float v1 = acc[a][1] + bv.y + uvi + vv[tj * 4 + 1];
      float v2 = acc[a][2] + bv.z + uvi + vv[tj * 4 + 2];
      float v3 = acc[a][3] + bv.w + uvi + vv[tj * 4 + 3];
      float m = fmaxf(fmaxf(v0, v1), fmaxf(v2, v3));
#pragma unroll
      for (int o = 16; o > 0; o >>= 1) m = fmaxf(m, __shfl_xor(m, o));
      float e0 = __expf(v0 - m), e1 = __expf(v1 - m), e2 = __expf(v2 - m), e3 = __expf(v3 - m);
      float s = e0 + e1 + e2 + e3;
#pragma unroll
      for (int o = 16; o > 0; o >>= 1) s += __shfl_xor(s, o);
      float inv = 1.f / s;
      p[a][0] = e0 * inv; p[a][1] = e1 * inv; p[a][2] = e2 * inv; p[a][3] = e3 * inv;
    }
  }
  __syncthreads();
  float* P = Lh;
  if (act) {
#pragma unroll
    for (int a = 0; a < 4; a++)
      *(float4*)&P[(ti * 4 + a) * 132 + tj * 4] = make_float4(p[a][0], p[a][1], p[a][2], p[a][3]);
  }
  __syncthreads();

  int tn = tid & 15, i2 = tid >> 4;
  float o0 = 0, o1 = 0, o2 = 0, o3 = 0;
  const float* Prow = P + i2 * 132;
#pragma unroll 4
  for (int j = 0; j < 128; j++) {
    float4 xv = *(const float4*)&xsT[j * 68 + tn * 4];
    float pv = Prow[j];
    o0 += pv * xv.x; o1 += pv * xv.y; o2 += pv * xv.z; o3 += pv * xv.w;
  }
  float* hto = ht + (size_t)b * 8192 + (size_t)(i0 + i2) * 64 + tn * 4;
  *(float4*)hto = make_float4(tanhf(o0), tanhf(o1), tanhf(o2), tanhf(o3));
}

// ================= K4: GAT via rank-1 pullthrough =================
__global__ __launch_bounds__(512) void k_gat2(const float* __restrict__ ht, const float* __restrict__ VAV,
                                              const int* __restrict__ off, const int* __restrict__ list,
                                              const float* __restrict__ fcb, float* __restrict__ outp) {
  __shared__ float htT[64 * 132];
  __shared__ float va_s[128], vd_s[128], vf_s[128];
  __shared__ float ss_s[64], sd_s[64], pf_s[64];
  __shared__ int offs_s[65];
  __shared__ int list_s[1408];
  __shared__ float gbfc_s;
  int tid = threadIdx.x, b = blockIdx.x;
  const float* hb = ht + (size_t)b * 8192;
  for (int t = tid; t < 8192; t += 512) {
    int w = t >> 6, n = t & 63;
    htT[n * 132 + w] = hb[t];
  }
  if (tid < 128) {
    va_s[tid] = VAV[tid];
    vd_s[tid] = VAV[128 + tid];
    vf_s[tid] = VAV[256 + tid];
  }
  if (tid == 0) gbfc_s = VAV[384];
  if (tid < 65) offs_s[tid] = off[tid];
  __syncthreads();
  int totE = offs_s[64];
  for (int t = tid; t < totE; t += 512) list_s[t] = list[t];

  {
    int n = tid >> 3, oct = tid & 7;
    const float* hr = htT + n * 132 + oct * 16;
    float s1 = 0, s2 = 0, s3 = 0;
#pragma unroll 4
    for (int k = 0; k < 16; k++) {
      float h = hr[k];
      int w = oct * 16 + k;
      s1 += h * va_s[w]; s2 += h * vd_s[w]; s3 += h * vf_s[w];
    }
#pragma unroll
    for (int o = 4; o > 0; o >>= 1) {
      s1 += __shfl_xor(s1, o); s2 += __shfl_xor(s2, o); s3 += __shfl_xor(s3, o);
    }
    if (oct == 0) { ss_s[n] = s1; sd_s[n] = s2; pf_s[n] = s3; }
  }
  __syncthreads();

  if (tid < 64) {
    int e0 = offs_s[tid], e1 = offs_s[tid + 1];
    float sdv = sd_s[tid];
    float mx = -1e30f;
    for (int e = e0; e < e1; e++) {
      float t = ss_s[list_s[e]] + sdv;
      t = fmaxf(t, 0.2f * t);
      mx = fmaxf(mx, t);
    }
    float den = 0.f, acc = 0.f;
    for (int e = e0; e < e1; e++) {
      int s = list_s[e];
      float t = ss_s[s] + sdv;
      t = fmaxf(t, 0.2f * t);
      float w = __expf(t - mx);
      den += w;
      acc += w * pf_s[s];
    }
    outp[b * 64 + tid] = tanhf(acc / den + gbfc_s + fcb[0]);
  }
}

extern "C" void kernel_launch(void* const* d_in, const int* in_sizes, int n_in,
                              void* d_out, int out_size, void* d_ws, size_t ws_size,
                              hipStream_t stream) {
  (void)n_in; (void)out_size; (void)ws_size;
  const float* x        = (const float*)d_in[0];
  const float* gl_embed = (const float*)d_in[7];
  const float* gcn_w    = (const float*)d_in[8];
  const float* gcn_b    = (const float*)d_in[9];
  const float* mlp_w1   = (const float*)d_in[10];
  const float* mlp_b1   = (const float*)d_in[11];
  const float* mlp_w2   = (const float*)d_in[12];
  const float* mlp_b2   = (const float*)d_in[13];
  const float* ta_w     = (const float*)d_in[14];
  const float* ta_b     = (const float*)d_in[15];
  const float* ta_a     = (const float*)d_in[16];
  const float* ta_bias  = (const float*)d_in[17];
  const float* gat_w    = (const float*)d_in[18];
  const float* gat_asrc = (const float*)d_in[19];
  const float* gat_adst = (const float*)d_in[20];
  const float* gat_b    = (const float*)d_in[21];
  const float* fc_w     = (const float*)d_in[22];
  const float* fc_b     = (const float*)d_in[23];
  const int*   gat_ei   = (const int*)d_in[24];
  const int*   gl_ei    = (const int*)d_in[25];

  int E_gat = in_sizes[24] / (2 * BB);  // 1280
  int E_gl  = in_sizes[25] / (2 * BB);  // 1638

  float* ws = (float*)d_ws;
  float* XS    = ws + 0;        // 524288
  float* LEFT  = ws + 524288;   // 1048576
  float* RIGHT = ws + 1572864;  // 1048576
  float* HT    = ws + 2621440;  // 524288
  int*   IP    = (int*)(ws + 3145728);
  int* GATOFF  = IP;            // 72
  int* GATLIST = IP + 72;       // 2048
  float* VAV   = ws + 3148288;  // 512 (va|vd|vf|gbfc)

  float* out_rec = (float*)d_out;
  float* out_pre = (float*)d_out + 524288;

  k_front<<<256, 512, 0, stream>>>(x, gl_embed, gcn_w, gcn_b, mlp_w1, mlp_b1, mlp_w2, mlp_b2,
                                   gl_ei, E_gl, gat_ei, E_gat, XS, out_rec, GATOFF, GATLIST);
  k_lr<<<2051, 256, 0, stream>>>(XS, ta_w, ta_b, LEFT, RIGHT,
                                 gat_w, gat_asrc, gat_adst, fc_w, gat_b, VAV);
  k_attn<<<256, 512, 0, stream>>>(LEFT, RIGHT, ta_a, ta_bias, XS, HT);
  k_gat2<<<64, 512, 0, stream>>>(HT, VAV, GATOFF, GATLIST, fc_b, out_pre);
}

// Round 14
// 103.435 us; speedup vs baseline: 1.1411x; 1.1411x over previous
//
#include <hip/hip_runtime.h>
#include <math.h>

#define BB  64
#define WW  128
#define NN  64
#define HIDN 77

// ================= K1: fused front, fp32 weights, 1024 thr (16 waves/CU) =================
// hA=(S@[x|emb])@Wg -> MLP -> xs, out_rec. Block 1 tail-builds GAT CSR.
// LDS floats: Ws@0:17920 (later W2 77x128) | W1s@17920:10240 | XA@28160:2304 |
// Sm@30464:1088 | xbt@31552:2112 | hm@33664:1280 | recT@34944:2176 | gbb@37120:128 | cnt@37248:64
__global__ __launch_bounds__(1024) void k_front(
    const float* __restrict__ x, const float* __restrict__ emb,
    const float* __restrict__ wg, const float* __restrict__ gcn_b,
    const float* __restrict__ w1, const float* __restrict__ b1,
    const float* __restrict__ w2, const float* __restrict__ b2,
    const int* __restrict__ gl_ei, int E_gl,
    const int* __restrict__ gat_ei, int E_gat,
    float* __restrict__ xs, float* __restrict__ out_rec,
    int* __restrict__ gat_off, int* __restrict__ gat_list) {
  __shared__ float smem[37312];   // 149248 B
  float* Ws   = smem;
  float* W1s  = smem + 17920;
  float* XA   = smem + 28160;
  float* Sm   = smem + 30464;
  float* xbt  = smem + 31552;
  float* hm   = smem + 33664;
  float* recT = smem + 34944;
  float* gbb  = smem + 37120;
  int*   cnt  = (int*)(smem + 37248);
  float* scr4 = smem + 33664;   // P4 partials: 512*4 = 2048 f (over hm+recT front)
  float* scr6 = smem + 34944;   // P6 partials: 320*4 = 1280 f (over recT)

  int tid = threadIdx.x;
  int r0 = blockIdx.x * 16;
  int b = r0 >> 6, n0 = r0 & 63;
  const float* xb  = x + (size_t)b * 8192;
  const float* xb2 = xb + n0;

  // P0: stage Ws fp32, xbt; init Sm, cnt, gbb (W1 staged later, its region is P4 scratch-free)
  {
    const float4* W4 = (const float4*)wg;
    float4* Ws4 = (float4*)Ws;
    for (int t = tid; t < 4480; t += 1024) Ws4[t] = W4[t];
  }
  for (int t = tid; t < 2048; t += 1024) {
    int w = t >> 4, i = t & 15;
    xbt[i * 132 + w] = xb2[w * 64 + i];
  }
  for (int t = tid; t < 1088; t += 1024) Sm[t] = 0.f;
  if (tid < 128) gbb[tid] = gcn_b[tid];
  if (tid < 64) cnt[tid] = 1;  // self-loop
  __syncthreads();

  // P1: edge scan: degree + indicator
  for (int e = tid; e < E_gl; e += 1024) {
    int dst = gl_ei[BB * E_gl + e];
    atomicAdd(&cnt[dst], 1);
    int d = dst - n0;
    if ((unsigned)d < 16u) Sm[d * 68 + gl_ei[e]] = 1.0f;
  }
  __syncthreads();

  // P2: scale indicators -> coefs + self-loop
  for (int t = tid; t < 1088; t += 1024) {
    int i = t / 68, s = t % 68;
    if (s < 64) {
      float di = rsqrtf((float)cnt[n0 + i]);
      float v = Sm[t] * rsqrtf((float)cnt[s]) * di;
      if (s == n0 + i) v += di * di;
      Sm[t] = v;
    }
  }
  __syncthreads();

  // P3: XA[i][w] = sum_s Sm[i][s]*x[b][w][s]; thread = (row i, w in {tw, tw+64})
  {
    int i = tid >> 6, tw = tid & 63;
    const float* Sr = Sm + i * 68;
    float o0 = 0, o1 = 0;
#pragma unroll 4
    for (int s4 = 0; s4 < 16; s4++) {
      float4 sv = *(const float4*)&Sr[s4 * 4];
      float4 x0 = *(const float4*)&xb[tw * 64 + s4 * 4];
      float4 x1 = *(const float4*)&xb[(tw + 64) * 64 + s4 * 4];
      o0 += sv.x * x0.x + sv.y * x0.y + sv.z * x0.z + sv.w * x0.w;
      o1 += sv.x * x1.x + sv.y * x1.y + sv.z * x1.z + sv.w * x1.w;
    }
    float* Xr = XA + i * 144;
    Xr[tw] = o0; Xr[tw + 64] = o1;
  }
  if (tid < 192) {
    int i = tid / 12, j = tid % 12;
    const float* Sr = Sm + i * 68;
    float a = 0.f;
    for (int s = 0; s < 64; s++) a += Sr[s] * emb[s * 12 + j];
    XA[i * 144 + 128 + j] = a;
  }
  __syncthreads();

  // P4: GEMM1 (16x140 @ 140x128), 1r x 4c x k-split-2 over 1024 threads
  {
    int half = tid >> 9, t = tid & 511;
    int row = t >> 5, cg = t & 31;
    int c0 = cg * 4;
    float a0 = 0, a1 = 0, a2 = 0, a3 = 0;
    const float* Ar = XA + row * 144;
    int k0 = half * 70;
#pragma unroll 5
    for (int k = k0; k < k0 + 70; k++) {
      float4 wv = *(const float4*)&Ws[k * 128 + c0];
      float a = Ar[k];
      a0 += a * wv.x; a1 += a * wv.y; a2 += a * wv.z; a3 += a * wv.w;
    }
    if (half) *(float4*)&scr4[t * 4] = make_float4(a0, a1, a2, a3);
    __syncthreads();   // all Ws/XA reads + scr4 writes done
    if (!half) {
      float4 p = *(const float4*)&scr4[t * 4];
      float4 bv = *(const float4*)&gbb[c0];
      *(float4*)&XA[row * 144 + c0] = make_float4(
          fmaxf(a0 + p.x + bv.x, 0.f), fmaxf(a1 + p.y + bv.y, 0.f),
          fmaxf(a2 + p.z + bv.z, 0.f), fmaxf(a3 + p.w + bv.w, 0.f));
    }
    // stage W1 (region disjoint from scr4)
    for (int q = tid; q < 10240; q += 1024) {
      int k = q / 80, c = q % 80;
      W1s[q] = (c < HIDN) ? w1[k * HIDN + c] : 0.f;
    }
  }
  __syncthreads();

  // P6: hm = tanh(hA @ W1 + b1), 1r x 4c x k-split-2, 640 active threads
  {
    bool act = tid < 640;
    int half6 = (tid >= 320) ? 1 : 0;
    int s = act ? (half6 ? tid - 320 : tid) : 0;
    int rp = s / 20, cg = s % 20;
    int c0 = cg * 4;
    float a0 = 0, a1 = 0, a2 = 0, a3 = 0;
    if (act) {
      const float* Ar = XA + rp * 144;
      int k0 = half6 * 64;
#pragma unroll 4
      for (int k = k0; k < k0 + 64; k++) {
        float4 wv = *(const float4*)&W1s[k * 80 + c0];
        float a = Ar[k];
        a0 += a * wv.x; a1 += a * wv.y; a2 += a * wv.z; a3 += a * wv.w;
      }
      if (half6) *(float4*)&scr6[s * 4] = make_float4(a0, a1, a2, a3);
    }
    __syncthreads();
    if (act && !half6) {
      float4 p = *(const float4*)&scr6[s * 4];
      float rv[4] = {a0 + p.x, a1 + p.y, a2 + p.z, a3 + p.w};
#pragma unroll
      for (int j = 0; j < 4; j++) {
        int c = c0 + j;
        float bb = (c < HIDN) ? b1[c] : 0.f;
        hm[rp * 80 + c] = tanhf(rv[j] + bb);
      }
    }
  }
  __syncthreads();
  // P7: stage W2 over Ws base
  {
    const float4* w24 = (const float4*)w2;
    float4* Wb4 = (float4*)smem;
    for (int t = tid; t < 2464; t += 1024) Wb4[t] = w24[t];
  }
  __syncthreads();

  // P8: x_rec = tanh(hm @ W2 + b2); xs; recT  (1r x 4c, 512 active)
  {
    if (tid < 512) {
      int row = tid >> 5, cg = tid & 31;
      int c0 = cg * 4;
      float a0 = 0, a1 = 0, a2 = 0, a3 = 0;
      const float* Hr = hm + row * 80;
#pragma unroll 4
      for (int k = 0; k < HIDN; k++) {
        float4 wv = *(const float4*)&smem[k * 128 + c0];   // W2 at Ws base
        float a = Hr[k];
        a0 += a * wv.x; a1 += a * wv.y; a2 += a * wv.z; a3 += a * wv.w;
      }
      float4 bv = *(const float4*)&b2[c0];
      float x0 = tanhf(a0 + bv.x), x1 = tanhf(a1 + bv.y);
      float x2 = tanhf(a2 + bv.z), x3 = tanhf(a3 + bv.w);
      const float* X0 = xbt + row * 132;
      *(float4*)&xs[(size_t)(r0 + row) * 128 + c0] =
          make_float4(X0[c0] + x0, X0[c0 + 1] + x1, X0[c0 + 2] + x2, X0[c0 + 3] + x3);
      recT[(c0 + 0) * 17 + row] = x0; recT[(c0 + 1) * 17 + row] = x1;
      recT[(c0 + 2) * 17 + row] = x2; recT[(c0 + 3) * 17 + row] = x3;
    }
  }
  __syncthreads();
  // P9: out_rec
  float* orc = out_rec + (size_t)b * 8192 + n0;
  for (int t = tid; t < 2048; t += 1024) {
    int w = t >> 4, i = t & 15;
    orc[w * 64 + i] = recT[w * 17 + i];
  }

  // ---- tail (block 1): build GAT CSR ----
  if (blockIdx.x == 1) {
    __syncthreads();
    int* ip   = (int*)smem;
    int* offs = ip;
    int* cur  = ip + 65;
    int* cntg = ip + 129;
    int* lst  = ip + 193;
    if (tid < 64) cntg[tid] = 1;
    __syncthreads();
    for (int e = tid; e < E_gat; e += 1024) atomicAdd(&cntg[gat_ei[BB * E_gat + e]], 1);
    __syncthreads();
    if (tid == 0) { int s = 0; for (int n = 0; n < 64; n++) { offs[n] = s; s += cntg[n]; } offs[64] = s; }
    __syncthreads();
    if (tid < 64) cur[tid] = offs[tid];
    __syncthreads();
    for (int e = tid; e < E_gat; e += 1024) {
      int src = gat_ei[e], dst = gat_ei[BB * E_gat + e];
      lst[atomicAdd(&cur[dst], 1)] = src;
    }
    if (tid < 64) lst[atomicAdd(&cur[tid], 1)] = tid;
    __syncthreads();
    if (tid < 65) gat_off[tid] = offs[tid];
    int tot = offs[64];
    for (int t = tid; t < tot; t += 1024) gat_list[t] = lst[t];
  }
}

// ================= K2: left/right projections + (blocks>=2048) GAT matvecs =================
__global__ __launch_bounds__(256) void k_lr(const float* __restrict__ xs, const float* __restrict__ ta_w,
                                            const float* __restrict__ ta_b, float* __restrict__ leftT,
                                            float* __restrict__ rightT,
                                            const float* __restrict__ gat_w, const float* __restrict__ asrc,
                                            const float* __restrict__ adst, const float* __restrict__ fcw,
                                            const float* __restrict__ gat_b, float* __restrict__ VAV) {
  if (blockIdx.x >= 2048) {
    int which = blockIdx.x - 2048;
    int tid = threadIdx.x;
    const float* vecg = (which == 0) ? asrc : (which == 1) ? adst : fcw;
    if (tid < 128) {
      float acc = 0.f;
#pragma unroll 4
      for (int k = 0; k < 128; k++) acc += gat_w[tid * 128 + k] * vecg[k];
      VAV[which * 128 + tid] = acc;
    }
    if (which == 2) {
      __shared__ float red[128];
      if (tid < 128) red[tid] = gat_b[tid] * fcw[tid];
      __syncthreads();
      if (tid == 0) {
        float s = 0.f;
        for (int i = 0; i < 128; i++) s += red[i];
        VAV[384] = s;
      }
    }
    return;
  }
  int wave = threadIdx.x >> 6, lane = threadIdx.x & 63;
  int idx = blockIdx.x * 4 + wave;
  int b = idx >> 7, e = idx & 127;
  int c = lane * 2;
  const float* xsb = xs + (size_t)b * 8192;
  float lx = 0, ly = 0, rx = 0, ry = 0;
#pragma unroll 4
  for (int n = 0; n < 64; n++) {
    float wl = ta_w[n * 128 + e];
    float wr = ta_w[(64 + n) * 128 + e];
    float2 xv = *(const float2*)&xsb[n * 128 + c];
    lx += wl * xv.x; ly += wl * xv.y;
    rx += wr * xv.x; ry += wr * xv.y;
  }
  float tb = ta_b[e];
  *(float2*)&leftT[((size_t)b * 128 + e) * 128 + c] = make_float2(lx + tb, ly + tb);
  *(float2*)&rightT[((size_t)b * 128 + e) * 128 + c] = make_float2(rx, ry);
}

// ================= K3: fused e-score (4x4 tile) + softmax + PV + tanh =================
__global__ __launch_bounds__(512) void k_attn(const float* __restrict__ LEFT_, const float* __restrict__ RIGHT_,
                                              const float* __restrict__ ta_a, const float* __restrict__ ta_bias,
                                              const float* __restrict__ xs, float* __restrict__ ht) {
  __shared__ float Rf[128 * 128];
  __shared__ float Lh[32 * 132];
  __shared__ float xsT[128 * 68];
  __shared__ float av2[128], av6[128], uu[32], vv[128];
  int tid = threadIdx.x;
  int b = blockIdx.x >> 2, q = blockIdx.x & 3;
  int i0 = q * 32;

  {
    const float4* R4 = (const float4*)(RIGHT_ + (size_t)b * 16384);
    float4* Rf4 = (float4*)Rf;
#pragma unroll
    for (int t = 0; t < 8; t++) Rf4[tid + t * 512] = R4[tid + t * 512];
  }
  {
    const float* Lp = LEFT_ + (size_t)b * 16384 + i0;
#pragma unroll
    for (int t = 0; t < 8; t++) {
      int idx = tid + t * 512;
      Lh[idx] = Lp[(idx >> 5) * 128 + (idx & 31)];
    }
  }
  {
    const float* xsb = xs + (size_t)b * 8192;
#pragma unroll
    for (int t = 0; t < 16; t++) {
      int idx = tid + t * 512;
      xsT[(idx & 127) * 68 + (idx >> 7)] = xsb[idx];
    }
  }
  if (tid < 128) { float a = ta_a[tid]; av2[tid] = 0.4f * a; av6[tid] = 0.6f * a; }
  __syncthreads();

  if (tid < 160) {
    float acc = 0.f;
    if (tid < 128) {
      for (int e = 0; e < 128; e++) acc += av6[e] * Rf[e * 128 + tid];
      vv[tid] = acc;
    } else {
      int i = tid - 128;
      for (int e = 0; e < 128; e++) acc += av6[e] * Lh[e * 32 + i];
      uu[i] = acc;
    }
  }
  __syncthreads();

  bool act = tid < 256;
  int tj = tid & 31, ti = (tid >> 5) & 7;
  float p[4][4];
  if (act) {
    float acc[4][4];
#pragma unroll
    for (int a = 0; a < 4; a++)
#pragma unroll
      for (int j = 0; j < 4; j++) acc[a][j] = 0.f;
#pragma unroll 2
    for (int e = 0; e < 128; e++) {
      float4 Lv = *(const float4*)&Lh[e * 32 + ti * 4];
      float4 Rv = *(const float4*)&Rf[e * 128 + tj * 4];
      float ae = av2[e];
      float La[4] = {Lv.x, Lv.y, Lv.z, Lv.w};
      float Ra[4] = {Rv.x, Rv.y, Rv.z, Rv.w};
#pragma unroll
      for (int a = 0; a < 4; a++)
#pragma unroll
        for (int j = 0; j < 4; j++) {
          float t = La[a] + Ra[j];
          acc[a][j] += ae * fabsf(t);
        }
    }
#pragma unroll
    for (int a = 0; a < 4; a++) {
      int i = i0 + ti * 4 + a;
      float uvi = uu[ti * 4 + a];
      float4 bv = *(const float4*)&ta_bias[(size_t)i * 128 + tj * 4];
      float v0 = acc[a][0] + bv.x + uvi + vv[tj * 4 + 0];
      float v1 = acc[a][1] + bv.y + uvi + vv[tj * 4 + 1];
      float v2 = acc[a][2] + bv.z + uvi + vv[tj * 4 + 2];
      float v3 = acc[a][3] + bv.w + uvi + vv[tj * 4 + 3];
      float m = fmaxf(fmaxf(v0, v1), fmaxf(v2, v3));
#pragma unroll
      for (int o = 16; o > 0; o >>= 1) m = fmaxf(m, __shfl_xor(m, o));
      float e0 = __expf(v0 - m), e1 = __expf(v1 - m), e2 = __expf(v2 - m), e3 = __expf(v3 - m);
      float s = e0 + e1 + e2 + e3;
#pragma unroll
      for (int o = 16; o > 0; o >>= 1) s += __shfl_xor(s, o);
      float inv = 1.f / s;
      p[a][0] = e0 * inv; p[a][1] = e1 * inv; p[a][2] = e2 * inv; p[a][3] = e3 * inv;
    }
  }
  __syncthreads();
  float* P = Lh;
  if (act) {
#pragma unroll
    for (int a = 0; a < 4; a++)
      *(float4*)&P[(ti * 4 + a) * 132 + tj * 4] = make_float4(p[a][0], p[a][1], p[a][2], p[a][3]);
  }
  __syncthreads();

  int tn = tid & 15, i2 = tid >> 4;
  float o0 = 0, o1 = 0, o2 = 0, o3 = 0;
  const float* Prow = P + i2 * 132;
#pragma unroll 4
  for (int j = 0; j < 128; j++) {
    float4 xv = *(const float4*)&xsT[j * 68 + tn * 4];
    float pv = Prow[j];
    o0 += pv * xv.x; o1 += pv * xv.y; o2 += pv * xv.z; o3 += pv * xv.w;
  }
  float* hto = ht + (size_t)b * 8192 + (size_t)(i0 + i2) * 64 + tn * 4;
  *(float4*)hto = make_float4(tanhf(o0), tanhf(o1), tanhf(o2), tanhf(o3));
}

// ================= K4: GAT via rank-1 pullthrough =================
__global__ __launch_bounds__(512) void k_gat2(const float* __restrict__ ht, const float* __restrict__ VAV,
                                              const int* __restrict__ off, const int* __restrict__ list,
                                              const float* __restrict__ fcb, float* __restrict__ outp) {
  __shared__ float htT[64 * 132];
  __shared__ float va_s[128], vd_s[128], vf_s[128];
  __shared__ float ss_s[64], sd_s[64], pf_s[64];
  __shared__ int offs_s[65];
  __shared__ int list_s[1408];
  __shared__ float gbfc_s;
  int tid = threadIdx.x, b = blockIdx.x;
  const float* hb = ht + (size_t)b * 8192;
  for (int t = tid; t < 8192; t += 512) {
    int w = t >> 6, n = t & 63;
    htT[n * 132 + w] = hb[t];
  }
  if (tid < 128) {
    va_s[tid] = VAV[tid];
    vd_s[tid] = VAV[128 + tid];
    vf_s[tid] = VAV[256 + tid];
  }
  if (tid == 0) gbfc_s = VAV[384];
  if (tid < 65) offs_s[tid] = off[tid];
  __syncthreads();
  int totE = offs_s[64];
  for (int t = tid; t < totE; t += 512) list_s[t] = list[t];

  {
    int n = tid >> 3, oct = tid & 7;
    const float* hr = htT + n * 132 + oct * 16;
    float s1 = 0, s2 = 0, s3 = 0;
#pragma unroll 4
    for (int k = 0; k < 16; k++) {
      float h = hr[k];
      int w = oct * 16 + k;
      s1 += h * va_s[w]; s2 += h * vd_s[w]; s3 += h * vf_s[w];
    }
#pragma unroll
    for (int o = 4; o > 0; o >>= 1) {
      s1 += __shfl_xor(s1, o); s2 += __shfl_xor(s2, o); s3 += __shfl_xor(s3, o);
    }
    if (oct == 0) { ss_s[n] = s1; sd_s[n] = s2; pf_s[n] = s3; }
  }
  __syncthreads();

  if (tid < 64) {
    int e0 = offs_s[tid], e1 = offs_s[tid + 1];
    float sdv = sd_s[tid];
    float mx = -1e30f;
    for (int e = e0; e < e1; e++) {
      float t = ss_s[list_s[e]] + sdv;
      t = fmaxf(t, 0.2f * t);
      mx = fmaxf(mx, t);
    }
    float den = 0.f, acc = 0.f;
    for (int e = e0; e < e1; e++) {
      int s = list_s[e];
      float t = ss_s[s] + sdv;
      t = fmaxf(t, 0.2f * t);
      float w = __expf(t - mx);
      den += w;
      acc += w * pf_s[s];
    }
    outp[b * 64 + tid] = tanhf(acc / den + gbfc_s + fcb[0]);
  }
}

extern "C" void kernel_launch(void* const* d_in, const int* in_sizes, int n_in,
                              void* d_out, int out_size, void* d_ws, size_t ws_size,
                              hipStream_t stream) {
  (void)n_in; (void)out_size; (void)ws_size;
  const float* x        = (const float*)d_in[0];
  const float* gl_embed = (const float*)d_in[7];
  const float* gcn_w    = (const float*)d_in[8];
  const float* gcn_b    = (const float*)d_in[9];
  const float* mlp_w1   = (const float*)d_in[10];
  const float* mlp_b1   = (const float*)d_in[11];
  const float* mlp_w2   = (const float*)d_in[12];
  const float* mlp_b2   = (const float*)d_in[13];
  const float* ta_w     = (const float*)d_in[14];
  const float* ta_b     = (const float*)d_in[15];
  const float* ta_a     = (const float*)d_in[16];
  const float* ta_bias  = (const float*)d_in[17];
  const float* gat_w    = (const float*)d_in[18];
  const float* gat_asrc = (const float*)d_in[19];
  const float* gat_adst = (const float*)d_in[20];
  const float* gat_b    = (const float*)d_in[21];
  const float* fc_w     = (const float*)d_in[22];
  const float* fc_b     = (const float*)d_in[23];
  const int*   gat_ei   = (const int*)d_in[24];
  const int*   gl_ei    = (const int*)d_in[25];

  int E_gat = in_sizes[24] / (2 * BB);  // 1280
  int E_gl  = in_sizes[25] / (2 * BB);  // 1638

  float* ws = (float*)d_ws;
  float* XS    = ws + 0;        // 524288
  float* LEFT  = ws + 524288;   // 1048576
  float* RIGHT = ws + 1572864;  // 1048576
  float* HT    = ws + 2621440;  // 524288
  int*   IP    = (int*)(ws + 3145728);
  int* GATOFF  = IP;            // 72
  int* GATLIST = IP + 72;       // 2048
  float* VAV   = ws + 3148288;  // 512 (va|vd|vf|gbfc)

  float* out_rec = (float*)d_out;
  float* out_pre = (float*)d_out + 524288;

  k_front<<<256, 1024, 0, stream>>>(x, gl_embed, gcn_w, gcn_b, mlp_w1, mlp_b1, mlp_w2, mlp_b2,
                                    gl_ei, E_gl, gat_ei, E_gat, XS, out_rec, GATOFF, GATLIST);
  k_lr<<<2051, 256, 0, stream>>>(XS, ta_w, ta_b, LEFT, RIGHT,
                                 gat_w, gat_asrc, gat_adst, fc_w, gat_b, VAV);
  k_attn<<<256, 512, 0, stream>>>(LEFT, RIGHT, ta_a, ta_bias, XS, HT);
  k_gat2<<<64, 512, 0, stream>>>(HT, VAV, GATOFF, GATLIST, fc_b, out_pre);
}